// Round 21
// baseline (135.463 us; speedup 1.0000x reference)
//
#include <hip/hip_runtime.h>

#define NUM_EMB 1024
#define EMB_DIM 256

typedef __attribute__((ext_vector_type(8))) short short8v;
typedef _Float16 half8v __attribute__((ext_vector_type(8)));
typedef __attribute__((ext_vector_type(4))) float f32x4;
typedef unsigned long long u64;
typedef unsigned int u32;

__device__ __forceinline__ u32 sortable(float f) {
    u32 u = __float_as_uint(f);
    return (u & 0x80000000u) ? ~u : (u | 0x80000000u);
}
__device__ __forceinline__ float unsortable(u32 s) {
    u32 u = (s & 0x80000000u) ? (s & 0x7FFFFFFFu) : ~s;
    return __uint_as_float(u);
}
__device__ __forceinline__ u64 umin64(u64 a, u64 b) { return a < b ? a : b; }

// fp32 -> fp16 (RNE) bits and back
__device__ __forceinline__ unsigned short f2h_bits(float f) {
    _Float16 h = (_Float16)f;
    return *(unsigned short*)&h;
}
__device__ __forceinline__ float h2f(unsigned short b) {
    _Float16 h = *(_Float16*)&b;
    return (float)h;
}

#define GLP(p)  ((const __attribute__((address_space(1))) unsigned int*)(p))
#define LDSP(p) ((__attribute__((address_space(3))) unsigned int*)(p))

// ---- fused prep (r20-verbatim) ----
__global__ __launch_bounds__(512)
void vq_prep(const float* __restrict__ X, const float* __restrict__ E,
             float* __restrict__ ET, float* __restrict__ normE,
             char* __restrict__ Es, char* __restrict__ Xs,
             float* __restrict__ xl2arr, float* __restrict__ xh2arr,
             float* __restrict__ nx2arr, float* __restrict__ mxparts) {
    __shared__ float tile[64][65];
    __shared__ float mred[512];
    __shared__ float mred2[512];
    const int bid = blockIdx.x;
    const int t = threadIdx.x;
    if (bid < 64) {
        const int j0 = (bid & 15) * 64, d0 = (bid >> 4) * 64;
        const int tj = t & 63, td = t >> 6;
#pragma unroll
        for (int k = 0; k < 8; k++) {
            int dl = k * 8 + td;
            tile[dl][tj] = E[(d0 + dl) * NUM_EMB + j0 + tj];
        }
        __syncthreads();
        const int dd = t & 63, tw = t >> 6;
#pragma unroll
        for (int k = 0; k < 8; k++) {
            int jj = k * 8 + tw;
            ET[(j0 + jj) * EMB_DIM + d0 + dd] = tile[dd][jj];
        }
    } else if (bid < 66) {
        const int p = bid - 64;
        const int j = p * 512 + t;
        float s = 0.f, sel = 0.f;
#pragma unroll 8
        for (int d = 0; d < EMB_DIM; d++) {
            float v = E[d * NUM_EMB + j];
            s = fmaf(v, v, s);
            float el = v - h2f(f2h_bits(v));
            sel = fmaf(el, el, sel);
        }
        normE[j] = s;
        mred[t] = s;
        mred2[t] = sel;
        __syncthreads();
        for (int k = 256; k > 0; k >>= 1) {
            if (t < k) {
                mred[t] = fmaxf(mred[t], mred[t + k]);
                mred2[t] = fmaxf(mred2[t], mred2[t + k]);
            }
            __syncthreads();
        }
        if (t == 0) {
            mxparts[p] = mred[0];
            mxparts[2 + p] = mred2[0];
        }
    } else if (bid < 82) {
        const int rb = bid - 66;                // 0..15
        const int nblk = rb >> 2, ks = rb & 3;
#pragma unroll
        for (int i = 0; i < 4; i++) {
            int gid = i * 512 + t;
            int col = gid >> 3;
            int k8 = gid & 7;
            int kg = ks * 64 + k8 * 8;
            int colg = nblk * 256 + col;
            short8v v;
#pragma unroll
            for (int j = 0; j < 8; j++)
                v[j] = (short)f2h_bits(E[(kg + j) * NUM_EMB + colg]);
            size_t off = (size_t)nblk * 131072 + (size_t)ks * 32768 +
                         (size_t)(((col * 128 + (k8 * 8) * 2) ^ ((col & 7) << 4)));
            *(short8v*)(Es + off) = v;
        }
    } else {
        const int pb = bid - 82;                // 0..255
        const int mblk = pb >> 1;
        const int rhalf = (pb & 1) * 128;
#pragma unroll
        for (int i = 0; i < 8; i++) {
            int gid = i * 512 + t;
            int row = rhalf + (gid >> 5);
            int d0 = (gid & 31) * 8;
            const float4* xp4 = (const float4*)(X + ((size_t)mblk * 256 + row) * 256 + d0);
            float4 xa = xp4[0], xb = xp4[1];
            float xv[8] = {xa.x, xa.y, xa.z, xa.w, xb.x, xb.y, xb.z, xb.w};
            short8v vh;
            float sl = 0.f, sh = 0.f, sx = 0.f;
#pragma unroll
            for (int j = 0; j < 8; j++) {
                unsigned short hb = f2h_bits(xv[j]);
                vh[j] = (short)hb;
                float hf = h2f(hb);
                float xl = xv[j] - hf;
                sl = fmaf(xl, xl, sl);
                sh = fmaf(hf, hf, sh);
                sx = fmaf(xv[j], xv[j], sx);
            }
            int ksh = d0 >> 6, kl = d0 & 63;
            size_t inner = (size_t)(((row * 128 + kl * 2) ^ ((row & 7) << 4)));
            size_t base = (size_t)mblk * 131072;
            *(short8v*)(Xs + base + (size_t)ksh * 32768 + inner) = vh;
#pragma unroll
            for (int off = 16; off; off >>= 1) {
                sl += __shfl_xor(sl, off, 64);
                sh += __shfl_xor(sh, off, 64);
                sx += __shfl_xor(sx, off, 64);
            }
            if ((t & 31) == 0) {
                xl2arr[mblk * 256 + row] = sl;
                xh2arr[mblk * 256 + row] = sh;
                nx2arr[mblk * 256 + row] = sx;
            }
        }
    }
}

// ---- GEMM (fp16, K=256), SWAPPED operands: D = E x X (r15/r18/r20-verbatim) ----
__global__ __launch_bounds__(512, 1)
void vq_gemm(const char* __restrict__ Xs, const char* __restrict__ Es,
             const float* __restrict__ normE,
             u64* __restrict__ gkey, float* __restrict__ gm2) {
    extern __shared__ char smem[];
    const int t = threadIdx.x;
    const int bid = blockIdx.x;
    const int lbid = (bid & 7) * 64 + (bid >> 3);   // bijective: 512 = 8 XCD x 64
    const int mblk = lbid >> 2;
    const int nblk = lbid & 3;
    const int w = t >> 6, l = t & 63;
    const int lr = l & 15, lg = l >> 4;
    const int swz = (l & 7) << 4;

    const char* Bsrc = Es + (size_t)nblk * 131072;
    const char* Xg   = Xs + (size_t)mblk * 131072;

    const int eBase = lr * 128;
    const int xRow0 = (w * 32 + lr) * 128;
    const int xRow1 = (w * 32 + 16 + lr) * 128;

    f32x4 acc[2][16];
#pragma unroll
    for (int rt = 0; rt < 2; rt++)
#pragma unroll
        for (int ct = 0; ct < 16; ct++) acc[rt][ct] = (f32x4){0.f, 0.f, 0.f, 0.f};

#define GLL(srcp, dstoff) __builtin_amdgcn_global_load_lds(GLP(srcp), LDSP(smem + (dstoff)), 16, 0, 0)

#pragma unroll
    for (int q = 0; q < 16; q++)
        GLL(Bsrc + q * 8192 + t * 16, q * 8192 + t * 16);

    half8v xc0, xc1, xn0, xn1;
    {
        const int cf = (lg * 16) ^ swz;
        xc0 = *(const half8v*)(Xg + xRow0 + cf);
        xc1 = *(const half8v*)(Xg + xRow1 + cf);
    }
    asm volatile("s_waitcnt vmcnt(0)" ::: "memory");
    __builtin_amdgcn_s_barrier();
    asm volatile("" ::: "memory");

#define KSTEP(kc, XC0, XC1, XN0, XN1) {                                           \
    if ((kc) < 7) {                                                               \
        const int ks1 = ((kc) + 1) >> 1, h1 = ((kc) + 1) & 1;                     \
        const char* xg = Xg + ks1 * 32768;                                        \
        const int cfn = ((h1 * 64 + lg * 16) ^ swz);                              \
        XN0 = *(const half8v*)(xg + xRow0 + cfn);                                 \
        XN1 = *(const half8v*)(xg + xRow1 + cfn);                                 \
    }                                                                             \
    {                                                                             \
        const char* Eb = smem + ((kc) >> 1) * 32768;                              \
        const int cf0 = ((((kc) & 1) * 64 + lg * 16) ^ swz);                      \
        _Pragma("unroll")                                                         \
        for (int ct = 0; ct < 16; ct++) {                                         \
            half8v ef = *(const half8v*)(Eb + ct * 2048 + eBase + cf0);           \
            acc[0][ct] = __builtin_amdgcn_mfma_f32_16x16x32_f16(ef, XC0, acc[0][ct], 0, 0, 0); \
            acc[1][ct] = __builtin_amdgcn_mfma_f32_16x16x32_f16(ef, XC1, acc[1][ct], 0, 0, 0); \
        }                                                                         \
    }                                                                             \
}

    KSTEP(0, xc0, xc1, xn0, xn1);
    KSTEP(1, xn0, xn1, xc0, xc1);
    KSTEP(2, xc0, xc1, xn0, xn1);
    KSTEP(3, xn0, xn1, xc0, xc1);
    KSTEP(4, xc0, xc1, xn0, xn1);
    KSTEP(5, xn0, xn1, xc0, xc1);
    KSTEP(6, xc0, xc1, xn0, xn1);
    KSTEP(7, xn0, xn1, xc0, xc1);
#undef KSTEP
#undef GLL

    f32x4 ne4[16];
#pragma unroll
    for (int ct = 0; ct < 16; ct++)
        ne4[ct] = *(const f32x4*)(normE + nblk * 256 + ct * 16 + lg * 4);

#pragma unroll
    for (int rt = 0; rt < 2; rt++) {
        float m1 = __uint_as_float(0x7F7FFFFFu);
        float m2 = m1;
        u32 col = 0;
#pragma unroll
        for (int ct = 0; ct < 16; ct++) {
#pragma unroll
            for (int r = 0; r < 4; r++) {
                const float f = fmaf(-2.0f, acc[rt][ct][r], ne4[ct][r]);
                const float mx = fmaxf(m1, f);
                m2 = fminf(m2, mx);
                const bool p = f < m1;
                m1 = fminf(m1, f);
                const u32 cg = (u32)(nblk * 256 + ct * 16 + lg * 4 + r);
                col = p ? cg : col;
            }
        }
        u64 key = ((u64)sortable(m1) << 32) | col;
#pragma unroll
        for (int off = 16; off <= 32; off <<= 1) {
            const u64 ko = __shfl_xor(key, off, 64);
            const float m2o = __shfl_xor(m2, off, 64);
            const float m1a = unsortable((u32)(key >> 32));
            const float m1b = unsortable((u32)(ko >> 32));
            m2 = fminf(fminf(m2, m2o), fmaxf(m1a, m1b));
            key = umin64(key, ko);
        }
        if (l < 16) {
            const int rowg = mblk * 256 + w * 32 + rt * 16 + l;
            gkey[(size_t)nblk * 32768 + rowg] = key;
            gm2[(size_t)nblk * 32768 + rowg] = m2;
        }
    }
}

// ---- checkout: combine + in-block recheck (8-row batch, ILP-unrolled) + out-gather + loss partial ----
// grid 1024 x 512 thr; block owns rows [bid*32, bid*32+32)
__global__ __launch_bounds__(512)
void vq_checkout(const float* __restrict__ X, const float* __restrict__ E,
                 const float* __restrict__ normE,
                 const u64* __restrict__ gkey, const float* __restrict__ gm2,
                 const float* __restrict__ xl2arr, const float* __restrict__ xh2arr,
                 const float* __restrict__ nx2arr, const float* __restrict__ mxparts,
                 const float* __restrict__ ET,
                 float* __restrict__ out, float* __restrict__ partial) {
    __shared__ u32 sflags[32];
    __shared__ u32 snf;
    __shared__ u32 sidx[32];
    __shared__ float sd[32];
    __shared__ __align__(16) float xs4[8][256];
    __shared__ float r2part[8][32];
    __shared__ float r2s[8];
    __shared__ u64 wkey[8][8];

    const int t = threadIdx.x;
    const int row0 = (int)blockIdx.x * 32;
    if (t == 0) snf = 0;
    __syncthreads();

    // ---- combine + margin (r18-proven math), flags block-local ----
    if (t < 32) {
        const int row = row0 + t;
        u64 k_i[4]; float m2_i[4];
#pragma unroll
        for (int n = 0; n < 4; n++) {
            k_i[n] = gkey[(size_t)n * 32768 + row];
            m2_i[n] = gm2[(size_t)n * 32768 + row];
        }
        u64 K = umin64(umin64(k_i[0], k_i[1]), umin64(k_i[2], k_i[3]));
        float F1 = unsortable((u32)(K >> 32));
        float F2 = __uint_as_float(0x7F7FFFFFu);
#pragma unroll
        for (int n = 0; n < 4; n++) {
            float f1i = unsortable((u32)(k_i[n] >> 32));
            F2 = fminf(F2, (k_i[n] == K) ? m2_i[n] : f1i);
        }
        sidx[t] = (u32)(K & 0xFFFFFFFFu);
        sd[t] = F1;
        const float mEH = sqrtf(fmaxf(mxparts[0], mxparts[1]));
        const float mEL = sqrtf(fmaxf(mxparts[2], mxparts[3]));
        const float margin = 4.0f * (sqrtf(xh2arr[row]) * mEL + sqrtf(xl2arr[row]) * mEH) + 5e-4f;
        if (F2 - F1 < margin) {
            u32 p = atomicAdd(&snf, 1u);
            sflags[p] = (u32)t;          // local row index
        }
    }
    __syncthreads();
    const int n = (int)snf;

    // ---- exact fp32 recheck for flagged rows, batched 8, ILP-unrolled d-loop ----
    for (int b = 0; b < n; b += 8) {
        const int rem = n - b;
        const int nr = rem < 8 ? rem : 8;
        {
            const int r = t >> 6, li = t & 63;
            if (r < nr) {
                const int row = row0 + (int)sflags[b + r];
                ((float4*)xs4[r])[li] = ((const float4*)(X + (size_t)row * 256))[li];
            }
        }
        __syncthreads();
        if (t < 256) {
            const int r = t >> 5, li = t & 31;
            float s = 0.f;
#pragma unroll
            for (int k = 0; k < 8; k++) {
                float v = xs4[r][li * 8 + k];
                s = fmaf(v, v, s);
            }
            r2part[r][li] = s;
        }
        __syncthreads();
        if (t < 8) {
            float s = 0.f;
#pragma unroll
            for (int k = 0; k < 32; k++) s += r2part[t][k];
            r2s[t] = s;
        }
        __syncthreads();
        const int c0 = t * 2;
        float ax[8] = {0.f, 0.f, 0.f, 0.f, 0.f, 0.f, 0.f, 0.f};
        float ay[8] = {0.f, 0.f, 0.f, 0.f, 0.f, 0.f, 0.f, 0.f};
#pragma unroll 4
        for (int d = 0; d < 256; d += 4) {
            const float2 e0 = *(const float2*)(E + (d + 0) * NUM_EMB + c0);
            const float2 e1 = *(const float2*)(E + (d + 1) * NUM_EMB + c0);
            const float2 e2 = *(const float2*)(E + (d + 2) * NUM_EMB + c0);
            const float2 e3 = *(const float2*)(E + (d + 3) * NUM_EMB + c0);
#pragma unroll
            for (int r = 0; r < 8; r++) {
                const float4 xv = *(const float4*)(&xs4[r][d]);
                ax[r] = fmaf(xv.x, e0.x, ax[r]); ay[r] = fmaf(xv.x, e0.y, ay[r]);
                ax[r] = fmaf(xv.y, e1.x, ax[r]); ay[r] = fmaf(xv.y, e1.y, ay[r]);
                ax[r] = fmaf(xv.z, e2.x, ax[r]); ay[r] = fmaf(xv.z, e2.y, ay[r]);
                ax[r] = fmaf(xv.w, e3.x, ax[r]); ay[r] = fmaf(xv.w, e3.y, ay[r]);
            }
        }
        const float2 ne = *(const float2*)(normE + c0);
#pragma unroll
        for (int r = 0; r < 8; r++) {
            if (r < nr) {
                const float f0 = (r2s[r] + ne.x) - 2.0f * ax[r];
                const float f1 = (r2s[r] + ne.y) - 2.0f * ay[r];
                u64 k0 = ((u64)sortable(f0) << 32) | (u32)c0;
                u64 k1 = ((u64)sortable(f1) << 32) | (u32)(c0 + 1);
                u64 km = umin64(k0, k1);
#pragma unroll
                for (int off = 32; off; off >>= 1) km = umin64(km, __shfl_xor(km, off, 64));
                if ((t & 63) == 0) wkey[r][t >> 6] = km;
            }
        }
        __syncthreads();
        if (t < 8 && t < nr) {
            u64 m = wkey[t][0];
#pragma unroll
            for (int w2 = 1; w2 < 8; w2++) m = umin64(m, wkey[t][w2]);
            const int lrow = (int)sflags[b + t];
            sidx[lrow] = (u32)(m & 0xFFFFFFFFull);
            sd[lrow] = unsortable((u32)(m >> 32)) - r2s[t];   // exact dist - ||x||^2
        }
        __syncthreads();
    }

    // ---- loss partial: sum over 32 rows of nx2 + d ----
    if (t < 64) {
        float v = 0.f;
        if (t < 32) v = nx2arr[row0 + t] + sd[t];
#pragma unroll
        for (int off = 32; off; off >>= 1) v += __shfl_down(v, off, 64);
        if (t == 0) partial[blockIdx.x] = v;
    }

    // ---- out-gather: 32 rows x 256 cols ----
    const int dcol = t & 255, half = t >> 8;
    const long long base = (long long)row0 * 256;
#pragma unroll
    for (int rr = 0; rr < 16; rr++) {
        const int r = half * 16 + rr;
        out[base + r * 256 + dcol] = ET[(size_t)sidx[r] * EMB_DIM + dcol];
    }
}

// ---- finish: deterministic reduce of 1024 partials; loss = m + 0.25*m ----
__global__ void vq_finish(const float* __restrict__ partial, float* __restrict__ loss_out) {
    __shared__ float red[256];
    const int t = threadIdx.x;
    float s = 0.f;
    for (int i = t; i < 1024; i += 256) s += partial[i];
    red[t] = s;
    __syncthreads();
    for (int k = 128; k > 0; k >>= 1) {
        if (t < k) red[t] += red[t + k];
        __syncthreads();
    }
    if (t == 0) {
        const float m = red[0] / 8388608.0f;
        loss_out[0] = fmaf(0.25f, m, m);
    }
}

extern "C" void kernel_launch(void* const* d_in, const int* in_sizes, int n_in,
                              void* d_out, int out_size, void* d_ws, size_t ws_size,
                              hipStream_t stream) {
    const float* X = (const float*)d_in[0];      // (32,32,32,256) fp32
    const float* E = (const float*)d_in[1];      // (256,1024) fp32
    float* out = (float*)d_out;

    // workspace layout (bytes)
    char* ws = (char*)d_ws;
    float* ET       = (float*)(ws + 0);            // 1 MB
    float* normE    = (float*)(ws + 1048576);      // 4 KB
    float* partial  = (float*)(ws + 1052672);      // 4 KB (1024 floats)
    float* mxparts  = (float*)(ws + 1056768);      // 16 B
    char*  Es       = ws + 1060864;                // 512 KB
    u64*   gkey     = (u64*)(ws + 2109440);        // 1 MB
    float* gm2      = (float*)(ws + 3158016);      // 512 KB
    float* xl2arr   = (float*)(ws + 3682304);      // 128 KB
    float* xh2arr   = (float*)(ws + 3813376);      // 128 KB
    float* nx2arr   = (float*)(ws + 3944448);      // 128 KB (ends 4,075,520)

    // Xs fp16 panel (16 MB) aliases d_out; fully consumed by vq_gemm before vq_checkout writes out.
    char* Xs = (char*)d_out;

    vq_prep<<<338, 512, 0, stream>>>(X, E, ET, normE, Es, Xs, xl2arr, xh2arr, nx2arr, mxparts);
    vq_gemm<<<512, 512, 131072, stream>>>(Xs, Es, normE, gkey, gm2);
    vq_checkout<<<1024, 512, 0, stream>>>(X, E, normE, gkey, gm2, xl2arr, xh2arr, nx2arr,
                                          mxparts, ET, out, partial);
    vq_finish<<<1, 256, 0, stream>>>(partial, out + (out_size - 1));
}

// Round 22
// 97.320 us; speedup vs baseline: 1.3919x; 1.3919x over previous
//
#include <hip/hip_runtime.h>

#define NUM_EMB 1024
#define EMB_DIM 256

typedef __attribute__((ext_vector_type(8))) short short8v;
typedef _Float16 half8v __attribute__((ext_vector_type(8)));
typedef __attribute__((ext_vector_type(4))) float f32x4;
typedef unsigned long long u64;
typedef unsigned int u32;

__device__ __forceinline__ u32 sortable(float f) {
    u32 u = __float_as_uint(f);
    return (u & 0x80000000u) ? ~u : (u | 0x80000000u);
}
__device__ __forceinline__ float unsortable(u32 s) {
    u32 u = (s & 0x80000000u) ? (s & 0x7FFFFFFFu) : ~s;
    return __uint_as_float(u);
}
__device__ __forceinline__ u64 umin64(u64 a, u64 b) { return a < b ? a : b; }

// fp32 -> fp16 (RNE) bits and back
__device__ __forceinline__ unsigned short f2h_bits(float f) {
    _Float16 h = (_Float16)f;
    return *(unsigned short*)&h;
}
__device__ __forceinline__ float h2f(unsigned short b) {
    _Float16 h = *(_Float16*)&b;
    return (float)h;
}

#define GLP(p)  ((const __attribute__((address_space(1))) unsigned int*)(p))
#define LDSP(p) ((__attribute__((address_space(3))) unsigned int*)(p))

// ---- fused prep (r20-verbatim + cnt zeroing in bid 0) ----
__global__ __launch_bounds__(512)
void vq_prep(const float* __restrict__ X, const float* __restrict__ E,
             float* __restrict__ ET, float* __restrict__ normE,
             char* __restrict__ Es, char* __restrict__ Xs,
             float* __restrict__ xl2arr, float* __restrict__ xh2arr,
             float* __restrict__ nx2arr, float* __restrict__ mxparts,
             u32* __restrict__ cnt) {
    __shared__ float tile[64][65];
    __shared__ float mred[512];
    __shared__ float mred2[512];
    const int bid = blockIdx.x;
    const int t = threadIdx.x;
    if (bid == 0 && t == 0) *cnt = 0u;   // prep retires before combine launches
    if (bid < 64) {
        const int j0 = (bid & 15) * 64, d0 = (bid >> 4) * 64;
        const int tj = t & 63, td = t >> 6;
#pragma unroll
        for (int k = 0; k < 8; k++) {
            int dl = k * 8 + td;
            tile[dl][tj] = E[(d0 + dl) * NUM_EMB + j0 + tj];
        }
        __syncthreads();
        const int dd = t & 63, tw = t >> 6;
#pragma unroll
        for (int k = 0; k < 8; k++) {
            int jj = k * 8 + tw;
            ET[(j0 + jj) * EMB_DIM + d0 + dd] = tile[dd][jj];
        }
    } else if (bid < 66) {
        const int p = bid - 64;
        const int j = p * 512 + t;
        float s = 0.f, sel = 0.f;
#pragma unroll 8
        for (int d = 0; d < EMB_DIM; d++) {
            float v = E[d * NUM_EMB + j];
            s = fmaf(v, v, s);
            float el = v - h2f(f2h_bits(v));
            sel = fmaf(el, el, sel);
        }
        normE[j] = s;
        mred[t] = s;
        mred2[t] = sel;
        __syncthreads();
        for (int k = 256; k > 0; k >>= 1) {
            if (t < k) {
                mred[t] = fmaxf(mred[t], mred[t + k]);
                mred2[t] = fmaxf(mred2[t], mred2[t + k]);
            }
            __syncthreads();
        }
        if (t == 0) {
            mxparts[p] = mred[0];
            mxparts[2 + p] = mred2[0];
        }
    } else if (bid < 82) {
        const int rb = bid - 66;                // 0..15
        const int nblk = rb >> 2, ks = rb & 3;
#pragma unroll
        for (int i = 0; i < 4; i++) {
            int gid = i * 512 + t;
            int col = gid >> 3;
            int k8 = gid & 7;
            int kg = ks * 64 + k8 * 8;
            int colg = nblk * 256 + col;
            short8v v;
#pragma unroll
            for (int j = 0; j < 8; j++)
                v[j] = (short)f2h_bits(E[(kg + j) * NUM_EMB + colg]);
            size_t off = (size_t)nblk * 131072 + (size_t)ks * 32768 +
                         (size_t)(((col * 128 + (k8 * 8) * 2) ^ ((col & 7) << 4)));
            *(short8v*)(Es + off) = v;
        }
    } else {
        const int pb = bid - 82;                // 0..255
        const int mblk = pb >> 1;
        const int rhalf = (pb & 1) * 128;
#pragma unroll
        for (int i = 0; i < 8; i++) {
            int gid = i * 512 + t;
            int row = rhalf + (gid >> 5);
            int d0 = (gid & 31) * 8;
            const float4* xp4 = (const float4*)(X + ((size_t)mblk * 256 + row) * 256 + d0);
            float4 xa = xp4[0], xb = xp4[1];
            float xv[8] = {xa.x, xa.y, xa.z, xa.w, xb.x, xb.y, xb.z, xb.w};
            short8v vh;
            float sl = 0.f, sh = 0.f, sx = 0.f;
#pragma unroll
            for (int j = 0; j < 8; j++) {
                unsigned short hb = f2h_bits(xv[j]);
                vh[j] = (short)hb;
                float hf = h2f(hb);
                float xl = xv[j] - hf;
                sl = fmaf(xl, xl, sl);
                sh = fmaf(hf, hf, sh);
                sx = fmaf(xv[j], xv[j], sx);
            }
            int ksh = d0 >> 6, kl = d0 & 63;
            size_t inner = (size_t)(((row * 128 + kl * 2) ^ ((row & 7) << 4)));
            size_t base = (size_t)mblk * 131072;
            *(short8v*)(Xs + base + (size_t)ksh * 32768 + inner) = vh;
#pragma unroll
            for (int off = 16; off; off >>= 1) {
                sl += __shfl_xor(sl, off, 64);
                sh += __shfl_xor(sh, off, 64);
                sx += __shfl_xor(sx, off, 64);
            }
            if ((t & 31) == 0) {
                xl2arr[mblk * 256 + row] = sl;
                xh2arr[mblk * 256 + row] = sh;
                nx2arr[mblk * 256 + row] = sx;
            }
        }
    }
}

// ---- GEMM (fp16, K=256), SWAPPED operands: D = E x X (r15/r18-verbatim) ----
__global__ __launch_bounds__(512, 1)
void vq_gemm(const char* __restrict__ Xs, const char* __restrict__ Es,
             const float* __restrict__ normE,
             u64* __restrict__ gkey, float* __restrict__ gm2) {
    extern __shared__ char smem[];
    const int t = threadIdx.x;
    const int bid = blockIdx.x;
    const int lbid = (bid & 7) * 64 + (bid >> 3);   // bijective: 512 = 8 XCD x 64
    const int mblk = lbid >> 2;
    const int nblk = lbid & 3;
    const int w = t >> 6, l = t & 63;
    const int lr = l & 15, lg = l >> 4;
    const int swz = (l & 7) << 4;

    const char* Bsrc = Es + (size_t)nblk * 131072;
    const char* Xg   = Xs + (size_t)mblk * 131072;

    const int eBase = lr * 128;
    const int xRow0 = (w * 32 + lr) * 128;
    const int xRow1 = (w * 32 + 16 + lr) * 128;

    f32x4 acc[2][16];
#pragma unroll
    for (int rt = 0; rt < 2; rt++)
#pragma unroll
        for (int ct = 0; ct < 16; ct++) acc[rt][ct] = (f32x4){0.f, 0.f, 0.f, 0.f};

#define GLL(srcp, dstoff) __builtin_amdgcn_global_load_lds(GLP(srcp), LDSP(smem + (dstoff)), 16, 0, 0)

#pragma unroll
    for (int q = 0; q < 16; q++)
        GLL(Bsrc + q * 8192 + t * 16, q * 8192 + t * 16);

    half8v xc0, xc1, xn0, xn1;
    {
        const int cf = (lg * 16) ^ swz;
        xc0 = *(const half8v*)(Xg + xRow0 + cf);
        xc1 = *(const half8v*)(Xg + xRow1 + cf);
    }
    asm volatile("s_waitcnt vmcnt(0)" ::: "memory");
    __builtin_amdgcn_s_barrier();
    asm volatile("" ::: "memory");

#define KSTEP(kc, XC0, XC1, XN0, XN1) {                                           \
    if ((kc) < 7) {                                                               \
        const int ks1 = ((kc) + 1) >> 1, h1 = ((kc) + 1) & 1;                     \
        const char* xg = Xg + ks1 * 32768;                                        \
        const int cfn = ((h1 * 64 + lg * 16) ^ swz);                              \
        XN0 = *(const half8v*)(xg + xRow0 + cfn);                                 \
        XN1 = *(const half8v*)(xg + xRow1 + cfn);                                 \
    }                                                                             \
    {                                                                             \
        const char* Eb = smem + ((kc) >> 1) * 32768;                              \
        const int cf0 = ((((kc) & 1) * 64 + lg * 16) ^ swz);                      \
        _Pragma("unroll")                                                         \
        for (int ct = 0; ct < 16; ct++) {                                         \
            half8v ef = *(const half8v*)(Eb + ct * 2048 + eBase + cf0);           \
            acc[0][ct] = __builtin_amdgcn_mfma_f32_16x16x32_f16(ef, XC0, acc[0][ct], 0, 0, 0); \
            acc[1][ct] = __builtin_amdgcn_mfma_f32_16x16x32_f16(ef, XC1, acc[1][ct], 0, 0, 0); \
        }                                                                         \
    }                                                                             \
}

    KSTEP(0, xc0, xc1, xn0, xn1);
    KSTEP(1, xn0, xn1, xc0, xc1);
    KSTEP(2, xc0, xc1, xn0, xn1);
    KSTEP(3, xn0, xn1, xc0, xc1);
    KSTEP(4, xc0, xc1, xn0, xn1);
    KSTEP(5, xn0, xn1, xc0, xc1);
    KSTEP(6, xc0, xc1, xn0, xn1);
    KSTEP(7, xn0, xn1, xc0, xc1);
#undef KSTEP
#undef GLL

    f32x4 ne4[16];
#pragma unroll
    for (int ct = 0; ct < 16; ct++)
        ne4[ct] = *(const f32x4*)(normE + nblk * 256 + ct * 16 + lg * 4);

#pragma unroll
    for (int rt = 0; rt < 2; rt++) {
        float m1 = __uint_as_float(0x7F7FFFFFu);
        float m2 = m1;
        u32 col = 0;
#pragma unroll
        for (int ct = 0; ct < 16; ct++) {
#pragma unroll
            for (int r = 0; r < 4; r++) {
                const float f = fmaf(-2.0f, acc[rt][ct][r], ne4[ct][r]);
                const float mx = fmaxf(m1, f);
                m2 = fminf(m2, mx);
                const bool p = f < m1;
                m1 = fminf(m1, f);
                const u32 cg = (u32)(nblk * 256 + ct * 16 + lg * 4 + r);
                col = p ? cg : col;
            }
        }
        u64 key = ((u64)sortable(m1) << 32) | col;
#pragma unroll
        for (int off = 16; off <= 32; off <<= 1) {
            const u64 ko = __shfl_xor(key, off, 64);
            const float m2o = __shfl_xor(m2, off, 64);
            const float m1a = unsortable((u32)(key >> 32));
            const float m1b = unsortable((u32)(ko >> 32));
            m2 = fminf(fminf(m2, m2o), fmaxf(m1a, m1b));
            key = umin64(key, ko);
        }
        if (l < 16) {
            const int rowg = mblk * 256 + w * 32 + rt * 16 + l;
            gkey[(size_t)nblk * 32768 + rowg] = key;
            gm2[(size_t)nblk * 32768 + rowg] = m2;
        }
    }
}

// ---- combine: margin + idx + d_arr + flag (r18-verbatim, margin from mxparts) ----
__global__ __launch_bounds__(512) void vq_combine(const u64* __restrict__ gkey, const float* __restrict__ gm2,
                                                  const float* __restrict__ xl2arr, const float* __restrict__ xh2arr,
                                                  const float* __restrict__ mxparts,
                                                  u32* __restrict__ idx_arr, float* __restrict__ d_arr,
                                                  u32* __restrict__ flaglist, u32* __restrict__ cnt) {
    const int row = blockIdx.x * 512 + threadIdx.x;
    u64 k_i[4]; float m2_i[4];
#pragma unroll
    for (int n = 0; n < 4; n++) {
        k_i[n] = gkey[(size_t)n * 32768 + row];
        m2_i[n] = gm2[(size_t)n * 32768 + row];
    }
    u64 K = umin64(umin64(k_i[0], k_i[1]), umin64(k_i[2], k_i[3]));
    float F1 = unsortable((u32)(K >> 32));
    float F2 = __uint_as_float(0x7F7FFFFFu);
#pragma unroll
    for (int n = 0; n < 4; n++) {
        float f1i = unsortable((u32)(k_i[n] >> 32));
        F2 = fminf(F2, (k_i[n] == K) ? m2_i[n] : f1i);
    }
    idx_arr[row] = (u32)(K & 0xFFFFFFFFu);
    d_arr[row] = F1;
    const float mEH = sqrtf(fmaxf(mxparts[0], mxparts[1]));
    const float mEL = sqrtf(fmaxf(mxparts[2], mxparts[3]));
    const float margin = 4.0f * (sqrtf(xh2arr[row]) * mEL + sqrtf(xl2arr[row]) * mEH) + 5e-4f;
    if (F2 - F1 < margin) {
        u32 p = atomicAdd(cnt, 1u);
        flaglist[p] = (u32)row;
    }
}

// ---- exact fp32 recheck: separate kernel (r18 host), batch-8 + unroll-4 (r21-verified math) ----
__global__ __launch_bounds__(512) void vq_recheck(const float* __restrict__ X, const float* __restrict__ E,
                                                  const float* __restrict__ normE,
                                                  const u32* __restrict__ flaglist, const u32* __restrict__ cnt,
                                                  u32* __restrict__ idx_arr, float* __restrict__ d_arr) {
    __shared__ __align__(16) float xs4[8][256];
    __shared__ float r2part[8][32];
    __shared__ float r2s[8];
    __shared__ u64 wkey[8][8];
    const int t = threadIdx.x;
    const int n = (int)*cnt;
    const int nbatch = (n + 7) >> 3;
    for (int b = blockIdx.x; b < nbatch; b += 1024) {
        __syncthreads();
        const int rem = n - b * 8;
        const int nr = rem < 8 ? rem : 8;
        {
            const int r = t >> 6, li = t & 63;
            if (r < nr) {
                const int row = (int)flaglist[b * 8 + r];
                ((float4*)xs4[r])[li] = ((const float4*)(X + (size_t)row * 256))[li];
            }
        }
        __syncthreads();
        if (t < 256) {
            const int r = t >> 5, li = t & 31;
            float s = 0.f;
#pragma unroll
            for (int k = 0; k < 8; k++) {
                float v = xs4[r][li * 8 + k];
                s = fmaf(v, v, s);
            }
            r2part[r][li] = s;
        }
        __syncthreads();
        if (t < 8) {
            float s = 0.f;
#pragma unroll
            for (int k = 0; k < 32; k++) s += r2part[t][k];
            r2s[t] = s;
        }
        __syncthreads();
        const int c0 = t * 2;
        float ax[8] = {0.f, 0.f, 0.f, 0.f, 0.f, 0.f, 0.f, 0.f};
        float ay[8] = {0.f, 0.f, 0.f, 0.f, 0.f, 0.f, 0.f, 0.f};
#pragma unroll 4
        for (int d = 0; d < 256; d += 4) {
            const float2 e0 = *(const float2*)(E + (d + 0) * NUM_EMB + c0);
            const float2 e1 = *(const float2*)(E + (d + 1) * NUM_EMB + c0);
            const float2 e2 = *(const float2*)(E + (d + 2) * NUM_EMB + c0);
            const float2 e3 = *(const float2*)(E + (d + 3) * NUM_EMB + c0);
#pragma unroll
            for (int r = 0; r < 8; r++) {
                const float4 xv = *(const float4*)(&xs4[r][d]);
                ax[r] = fmaf(xv.x, e0.x, ax[r]); ay[r] = fmaf(xv.x, e0.y, ay[r]);
                ax[r] = fmaf(xv.y, e1.x, ax[r]); ay[r] = fmaf(xv.y, e1.y, ay[r]);
                ax[r] = fmaf(xv.z, e2.x, ax[r]); ay[r] = fmaf(xv.z, e2.y, ay[r]);
                ax[r] = fmaf(xv.w, e3.x, ax[r]); ay[r] = fmaf(xv.w, e3.y, ay[r]);
            }
        }
        const float2 ne = *(const float2*)(normE + c0);
#pragma unroll
        for (int r = 0; r < 8; r++) {
            if (r < nr) {
                const float f0 = (r2s[r] + ne.x) - 2.0f * ax[r];
                const float f1 = (r2s[r] + ne.y) - 2.0f * ay[r];
                u64 k0 = ((u64)sortable(f0) << 32) | (u32)c0;
                u64 k1 = ((u64)sortable(f1) << 32) | (u32)(c0 + 1);
                u64 km = umin64(k0, k1);
#pragma unroll
                for (int off = 32; off; off >>= 1) km = umin64(km, __shfl_xor(km, off, 64));
                if ((t & 63) == 0) wkey[r][t >> 6] = km;
            }
        }
        __syncthreads();
        if (t < 8 && t < nr) {
            u64 m = wkey[t][0];
#pragma unroll
            for (int w2 = 1; w2 < 8; w2++) m = umin64(m, wkey[t][w2]);
            const int row = (int)flaglist[b * 8 + t];
            idx_arr[row] = (u32)(m & 0xFFFFFFFFull);
            d_arr[row] = unsortable((u32)(m >> 32)) - r2s[t];   // exact dist - ||x||^2
        }
    }
}

// ---- out = gather(ET, idx); loss partial from nx2 + d_arr (r18-verbatim) ----
__global__ __launch_bounds__(512) void vq_out(const float* __restrict__ ET,
                                              const u32* __restrict__ idx_arr,
                                              const float* __restrict__ nx2arr, const float* __restrict__ d_arr,
                                              float* __restrict__ out, float* __restrict__ partial) {
    const int t = threadIdx.x;
    const long long base = (long long)blockIdx.x * 4096;   // 16 rows * 256
    const int dcol = t & 255, half = t >> 8;
    if (t < 64) {
        float v = 0.f;
        if (t < 16) {
            const int row = blockIdx.x * 16 + t;
            v = nx2arr[row] + d_arr[row];
        }
#pragma unroll
        for (int off = 32; off; off >>= 1) v += __shfl_down(v, off, 64);
        if (t == 0) partial[blockIdx.x] = v;
    }
#pragma unroll
    for (int rr = 0; rr < 8; rr++) {
        const int r = half * 8 + rr;
        const int row = blockIdx.x * 16 + r;
        const u32 idx = idx_arr[row];
        out[base + r * EMB_DIM + dcol] = ET[(size_t)idx * EMB_DIM + dcol];
    }
}

// ---- finish: loss = m + 0.25*m ----
__global__ void vq_finish(const float* __restrict__ partial, float* __restrict__ loss_out) {
    __shared__ float red[256];
    const int t = threadIdx.x;
    float s = 0.f;
    for (int i = t; i < 2048; i += 256) s += partial[i];
    red[t] = s;
    __syncthreads();
    for (int k = 128; k > 0; k >>= 1) {
        if (t < k) red[t] += red[t + k];
        __syncthreads();
    }
    if (t == 0) {
        const float m = red[0] / 8388608.0f;
        loss_out[0] = fmaf(0.25f, m, m);
    }
}

extern "C" void kernel_launch(void* const* d_in, const int* in_sizes, int n_in,
                              void* d_out, int out_size, void* d_ws, size_t ws_size,
                              hipStream_t stream) {
    const float* X = (const float*)d_in[0];      // (32,32,32,256) fp32
    const float* E = (const float*)d_in[1];      // (256,1024) fp32
    float* out = (float*)d_out;

    // workspace layout (bytes)
    char* ws = (char*)d_ws;
    float* ET       = (float*)(ws + 0);            // 1 MB
    float* normE    = (float*)(ws + 1048576);      // 4 KB
    float* partial  = (float*)(ws + 1052672);      // 8 KB (2048 floats)
    float* mxparts  = (float*)(ws + 1060868 - 4096);  // within gap before Es (16 B @1056772.. keep aligned below)
    char*  Es       = ws + 1060864;                // 512 KB
    u64*   gkey     = (u64*)(ws + 2109440);        // 1 MB
    float* gm2      = (float*)(ws + 3158016);      // 512 KB
    float* d_arr    = (float*)(ws + 3158016);      // aliases gm2 base (r18-proven safe)
    u32*   idx_arr  = (u32*)(ws + 3682304);        // 128 KB
    u32*   flaglist = (u32*)(ws + 3813376);        // 128 KB
    u32*   cnt      = (u32*)(ws + 3944448);        // 4 B
    float* nx2arr   = (float*)(ws + 3944960);      // 128 KB (ends 4,076,032 - proven extent)
    mxparts         = (float*)(ws + 3944452);      // 16 B (after cnt; within proven extent)

    // d_out upper region scratch: Xs fp16 panel (16 MB) + xl2/xh2 (consumed before vq_out).
    char*  Xs      = (char*)d_out;
    float* xl2arr  = (float*)((char*)d_out + 16777216);
    float* xh2arr  = (float*)((char*)d_out + 16777216 + 131072);

    vq_prep<<<338, 512, 0, stream>>>(X, E, ET, normE, Es, Xs, xl2arr, xh2arr, nx2arr,
                                     mxparts, cnt);
    vq_gemm<<<512, 512, 131072, stream>>>(Xs, Es, normE, gkey, gm2);
    vq_combine<<<64, 512, 0, stream>>>(gkey, gm2, xl2arr, xh2arr, mxparts,
                                       idx_arr, d_arr, flaglist, cnt);
    vq_recheck<<<1024, 512, 0, stream>>>(X, E, normE, flaglist, cnt, idx_arr, d_arr);
    vq_out<<<2048, 512, 0, stream>>>(ET, idx_arr, nx2arr, d_arr, out, partial);
    vq_finish<<<1, 256, 0, stream>>>(partial, out + (out_size - 1));
}

// Round 23
// 91.893 us; speedup vs baseline: 1.4741x; 1.0591x over previous
//
#include <hip/hip_runtime.h>

#define NUM_EMB 1024
#define EMB_DIM 256

typedef __attribute__((ext_vector_type(8))) short short8v;
typedef _Float16 half8v __attribute__((ext_vector_type(8)));
typedef __attribute__((ext_vector_type(4))) float f32x4;
typedef unsigned long long u64;
typedef unsigned int u32;

__device__ __forceinline__ u32 sortable(float f) {
    u32 u = __float_as_uint(f);
    return (u & 0x80000000u) ? ~u : (u | 0x80000000u);
}
__device__ __forceinline__ float unsortable(u32 s) {
    u32 u = (s & 0x80000000u) ? (s & 0x7FFFFFFFu) : ~s;
    return __uint_as_float(u);
}
__device__ __forceinline__ u64 umin64(u64 a, u64 b) { return a < b ? a : b; }

// fp32 -> fp16 (RNE) bits and back
__device__ __forceinline__ unsigned short f2h_bits(float f) {
    _Float16 h = (_Float16)f;
    return *(unsigned short*)&h;
}
__device__ __forceinline__ float h2f(unsigned short b) {
    _Float16 h = *(_Float16*)&b;
    return (float)h;
}

#define GLP(p)  ((const __attribute__((address_space(1))) unsigned int*)(p))
#define LDSP(p) ((__attribute__((address_space(3))) unsigned int*)(p))

// ---- fused prep ----
// bid 0      : (also) zero cnt
// bid 0..63  : transpose E -> ET
// bid 64..65 : normE; per-block max ||e||^2 / ||el||^2 -> mxparts (no atomics)
// bid 66..81 : eprep fp16 -> Es [nblk8 128 codes][ks 0..3][16KB tile: colL*128 + k*2 ^ swz]
// bid 82..337: xprep fp16 [mblk 128 of 256 rows][ks 0..3][32KB swizzled] + per-row norms
__global__ __launch_bounds__(512)
void vq_prep(const float* __restrict__ X, const float* __restrict__ E,
             float* __restrict__ ET, float* __restrict__ normE,
             char* __restrict__ Es, char* __restrict__ Xs,
             float* __restrict__ xl2arr, float* __restrict__ xh2arr,
             float* __restrict__ nx2arr, float* __restrict__ mxparts,
             u32* __restrict__ cnt) {
    __shared__ float tile[64][65];
    __shared__ float mred[512];
    __shared__ float mred2[512];
    const int bid = blockIdx.x;
    const int t = threadIdx.x;
    if (bid == 0 && t == 0) *cnt = 0u;   // prep retires before combine launches
    if (bid < 64) {
        const int j0 = (bid & 15) * 64, d0 = (bid >> 4) * 64;
        const int tj = t & 63, td = t >> 6;
#pragma unroll
        for (int k = 0; k < 8; k++) {
            int dl = k * 8 + td;
            tile[dl][tj] = E[(d0 + dl) * NUM_EMB + j0 + tj];
        }
        __syncthreads();
        const int dd = t & 63, tw = t >> 6;
#pragma unroll
        for (int k = 0; k < 8; k++) {
            int jj = k * 8 + tw;
            ET[(j0 + jj) * EMB_DIM + d0 + dd] = tile[dd][jj];
        }
    } else if (bid < 66) {
        const int p = bid - 64;
        const int j = p * 512 + t;
        float s = 0.f, sel = 0.f;
#pragma unroll 8
        for (int d = 0; d < EMB_DIM; d++) {
            float v = E[d * NUM_EMB + j];
            s = fmaf(v, v, s);
            float el = v - h2f(f2h_bits(v));
            sel = fmaf(el, el, sel);
        }
        normE[j] = s;
        mred[t] = s;
        mred2[t] = sel;
        __syncthreads();
        for (int k = 256; k > 0; k >>= 1) {
            if (t < k) {
                mred[t] = fmaxf(mred[t], mred[t + k]);
                mred2[t] = fmaxf(mred2[t], mred2[t + k]);
            }
            __syncthreads();
        }
        if (t == 0) {
            mxparts[p] = mred[0];
            mxparts[2 + p] = mred2[0];
        }
    } else if (bid < 82) {
#pragma unroll
        for (int i = 0; i < 4; i++) {
            const int gid2 = (bid - 66) * 2048 + i * 512 + t;   // 0..32767
            const int colG = gid2 >> 5;          // 0..1023
            const int k32 = gid2 & 31;
            const int ks = k32 >> 3, k8 = k32 & 7;
            short8v v;
#pragma unroll
            for (int j = 0; j < 8; j++)
                v[j] = (short)f2h_bits(E[(ks * 64 + k8 * 8 + j) * NUM_EMB + colG]);
            const int nb8 = colG >> 7, colL = colG & 127;
            size_t off = (size_t)nb8 * 65536 + (size_t)ks * 16384 +
                         (size_t)((colL * 128 + k8 * 16) ^ ((colL & 7) << 4));
            *(short8v*)(Es + off) = v;
        }
    } else {
        const int pb = bid - 82;                // 0..255
        const int mblk = pb >> 1;
        const int rhalf = (pb & 1) * 128;
#pragma unroll
        for (int i = 0; i < 8; i++) {
            int gid = i * 512 + t;
            int row = rhalf + (gid >> 5);
            int d0 = (gid & 31) * 8;
            const float4* xp4 = (const float4*)(X + ((size_t)mblk * 256 + row) * 256 + d0);
            float4 xa = xp4[0], xb = xp4[1];
            float xv[8] = {xa.x, xa.y, xa.z, xa.w, xb.x, xb.y, xb.z, xb.w};
            short8v vh;
            float sl = 0.f, sh = 0.f, sx = 0.f;
#pragma unroll
            for (int j = 0; j < 8; j++) {
                unsigned short hb = f2h_bits(xv[j]);
                vh[j] = (short)hb;
                float hf = h2f(hb);
                float xl = xv[j] - hf;
                sl = fmaf(xl, xl, sl);
                sh = fmaf(hf, hf, sh);
                sx = fmaf(xv[j], xv[j], sx);
            }
            int ksh = d0 >> 6, kl = d0 & 63;
            size_t inner = (size_t)(((row * 128 + kl * 2) ^ ((row & 7) << 4)));
            size_t base = (size_t)mblk * 131072;
            *(short8v*)(Xs + base + (size_t)ksh * 32768 + inner) = vh;
#pragma unroll
            for (int off = 16; off; off >>= 1) {
                sl += __shfl_xor(sl, off, 64);
                sh += __shfl_xor(sh, off, 64);
                sx += __shfl_xor(sx, off, 64);
            }
            if ((t & 31) == 0) {
                xl2arr[mblk * 256 + row] = sl;
                xh2arr[mblk * 256 + row] = sh;
                nx2arr[mblk * 256 + row] = sx;
            }
        }
    }
}

// ---- GEMM (fp16, K=256), SWAPPED: D = E x X; nblk split 8-way, LDS 64KB -> 2 blocks/CU ----
// grid 1024 = 128 mblk x 8 nblk (XCD swizzle); 512 thr, 8 waves x 32 rows
__global__ __launch_bounds__(512)
void vq_gemm(const char* __restrict__ Xs, const char* __restrict__ Es,
             const float* __restrict__ normE,
             u64* __restrict__ gkey, float* __restrict__ gm2) {
    extern __shared__ char smem[];
    const int t = threadIdx.x;
    const int bid = blockIdx.x;
    const int lbid = (bid & 7) * 128 + (bid >> 3);  // bijective: 1024 = 8 XCD x 128
    const int mblk = lbid >> 3;                      // 0..127
    const int nblk = lbid & 7;                       // 0..7
    const int w = t >> 6, l = t & 63;
    const int lr = l & 15, lg = l >> 4;
    const int swz = (l & 7) << 4;

    const char* Bsrc = Es + (size_t)nblk * 65536;
    const char* Xg   = Xs + (size_t)mblk * 131072;

    const int eBase = lr * 128;
    const int xRow0 = (w * 32 + lr) * 128;
    const int xRow1 = (w * 32 + 16 + lr) * 128;

    f32x4 acc[2][8];
#pragma unroll
    for (int rt = 0; rt < 2; rt++)
#pragma unroll
        for (int ct = 0; ct < 8; ct++) acc[rt][ct] = (f32x4){0.f, 0.f, 0.f, 0.f};

#define GLL(srcp, dstoff) __builtin_amdgcn_global_load_lds(GLP(srcp), LDSP(smem + (dstoff)), 16, 0, 0)

    // stage E panel (64KB) once
#pragma unroll
    for (int q = 0; q < 8; q++)
        GLL(Bsrc + q * 8192 + t * 16, q * 8192 + t * 16);

    half8v xc0, xc1, xn0, xn1;
    {
        const int cf = (lg * 16) ^ swz;
        xc0 = *(const half8v*)(Xg + xRow0 + cf);
        xc1 = *(const half8v*)(Xg + xRow1 + cf);
    }
    asm volatile("s_waitcnt vmcnt(0)" ::: "memory");
    __builtin_amdgcn_s_barrier();
    asm volatile("" ::: "memory");

#define KSTEP(kc, XC0, XC1, XN0, XN1) {                                           \
    if ((kc) < 7) {                                                               \
        const int ks1 = ((kc) + 1) >> 1, h1 = ((kc) + 1) & 1;                     \
        const char* xg = Xg + ks1 * 32768;                                        \
        const int cfn = ((h1 * 64 + lg * 16) ^ swz);                              \
        XN0 = *(const half8v*)(xg + xRow0 + cfn);                                 \
        XN1 = *(const half8v*)(xg + xRow1 + cfn);                                 \
    }                                                                             \
    {                                                                             \
        const char* Eb = smem + ((kc) >> 1) * 16384;                              \
        const int cf0 = ((((kc) & 1) * 64 + lg * 16) ^ swz);                      \
        _Pragma("unroll")                                                         \
        for (int ct = 0; ct < 8; ct++) {                                          \
            half8v ef = *(const half8v*)(Eb + ct * 2048 + eBase + cf0);           \
            acc[0][ct] = __builtin_amdgcn_mfma_f32_16x16x32_f16(ef, XC0, acc[0][ct], 0, 0, 0); \
            acc[1][ct] = __builtin_amdgcn_mfma_f32_16x16x32_f16(ef, XC1, acc[1][ct], 0, 0, 0); \
        }                                                                         \
    }                                                                             \
}

    KSTEP(0, xc0, xc1, xn0, xn1);
    KSTEP(1, xn0, xn1, xc0, xc1);
    KSTEP(2, xc0, xc1, xn0, xn1);
    KSTEP(3, xn0, xn1, xc0, xc1);
    KSTEP(4, xc0, xc1, xn0, xn1);
    KSTEP(5, xn0, xn1, xc0, xc1);
    KSTEP(6, xc0, xc1, xn0, xn1);
    KSTEP(7, xn0, xn1, xc0, xc1);
#undef KSTEP
#undef GLL

    // ---- epilogue: lane-local argmin over 32 codes (8 ct x 4 regs) ----
    f32x4 ne4[8];
#pragma unroll
    for (int ct = 0; ct < 8; ct++)
        ne4[ct] = *(const f32x4*)(normE + nblk * 128 + ct * 16 + lg * 4);

#pragma unroll
    for (int rt = 0; rt < 2; rt++) {
        float m1 = __uint_as_float(0x7F7FFFFFu);
        float m2 = m1;
        u32 col = 0;
#pragma unroll
        for (int ct = 0; ct < 8; ct++) {
#pragma unroll
            for (int r = 0; r < 4; r++) {
                const float f = fmaf(-2.0f, acc[rt][ct][r], ne4[ct][r]);
                const float mx = fmaxf(m1, f);
                m2 = fminf(m2, mx);
                const bool p = f < m1;
                m1 = fminf(m1, f);
                const u32 cg = (u32)(nblk * 128 + ct * 16 + lg * 4 + r);
                col = p ? cg : col;
            }
        }
        u64 key = ((u64)sortable(m1) << 32) | col;
#pragma unroll
        for (int off = 16; off <= 32; off <<= 1) {
            const u64 ko = __shfl_xor(key, off, 64);
            const float m2o = __shfl_xor(m2, off, 64);
            const float m1a = unsortable((u32)(key >> 32));
            const float m1b = unsortable((u32)(ko >> 32));
            m2 = fminf(fminf(m2, m2o), fmaxf(m1a, m1b));
            key = umin64(key, ko);
        }
        if (l < 16) {
            const int rowg = mblk * 256 + w * 32 + rt * 16 + l;
            gkey[(size_t)nblk * 32768 + rowg] = key;
            gm2[(size_t)nblk * 32768 + rowg] = m2;
        }
    }
}

// ---- combine: 8 segments -> margin + idx + d_arr + flag ----
__global__ __launch_bounds__(512) void vq_combine(const u64* __restrict__ gkey, const float* __restrict__ gm2,
                                                  const float* __restrict__ xl2arr, const float* __restrict__ xh2arr,
                                                  const float* __restrict__ mxparts,
                                                  u32* __restrict__ idx_arr, float* __restrict__ d_arr,
                                                  u32* __restrict__ flaglist, u32* __restrict__ cnt) {
    const int row = blockIdx.x * 512 + threadIdx.x;
    u64 k_i[8]; float m2_i[8];
#pragma unroll
    for (int n = 0; n < 8; n++) {
        k_i[n] = gkey[(size_t)n * 32768 + row];
        m2_i[n] = gm2[(size_t)n * 32768 + row];
    }
    u64 K = k_i[0];
#pragma unroll
    for (int n = 1; n < 8; n++) K = umin64(K, k_i[n]);
    float F1 = unsortable((u32)(K >> 32));
    float F2 = __uint_as_float(0x7F7FFFFFu);
#pragma unroll
    for (int n = 0; n < 8; n++) {
        float f1i = unsortable((u32)(k_i[n] >> 32));
        F2 = fminf(F2, (k_i[n] == K) ? m2_i[n] : f1i);
    }
    idx_arr[row] = (u32)(K & 0xFFFFFFFFu);
    d_arr[row] = F1;
    const float mEH = sqrtf(fmaxf(mxparts[0], mxparts[1]));
    const float mEL = sqrtf(fmaxf(mxparts[2], mxparts[3]));
    const float margin = 4.0f * (sqrtf(xh2arr[row]) * mEL + sqrtf(xl2arr[row]) * mEH) + 5e-4f;
    if (F2 - F1 < margin) {
        u32 p = atomicAdd(cnt, 1u);
        flaglist[p] = (u32)row;
    }
}

// ---- exact fp32 recheck: batch-8 + unroll-4 (r22-verified) ----
__global__ __launch_bounds__(512) void vq_recheck(const float* __restrict__ X, const float* __restrict__ E,
                                                  const float* __restrict__ normE,
                                                  const u32* __restrict__ flaglist, const u32* __restrict__ cnt,
                                                  u32* __restrict__ idx_arr, float* __restrict__ d_arr) {
    __shared__ __align__(16) float xs4[8][256];
    __shared__ float r2part[8][32];
    __shared__ float r2s[8];
    __shared__ u64 wkey[8][8];
    const int t = threadIdx.x;
    const int n = (int)*cnt;
    const int nbatch = (n + 7) >> 3;
    for (int b = blockIdx.x; b < nbatch; b += 1024) {
        __syncthreads();
        const int rem = n - b * 8;
        const int nr = rem < 8 ? rem : 8;
        {
            const int r = t >> 6, li = t & 63;
            if (r < nr) {
                const int row = (int)flaglist[b * 8 + r];
                ((float4*)xs4[r])[li] = ((const float4*)(X + (size_t)row * 256))[li];
            }
        }
        __syncthreads();
        if (t < 256) {
            const int r = t >> 5, li = t & 31;
            float s = 0.f;
#pragma unroll
            for (int k = 0; k < 8; k++) {
                float v = xs4[r][li * 8 + k];
                s = fmaf(v, v, s);
            }
            r2part[r][li] = s;
        }
        __syncthreads();
        if (t < 8) {
            float s = 0.f;
#pragma unroll
            for (int k = 0; k < 32; k++) s += r2part[t][k];
            r2s[t] = s;
        }
        __syncthreads();
        const int c0 = t * 2;
        float ax[8] = {0.f, 0.f, 0.f, 0.f, 0.f, 0.f, 0.f, 0.f};
        float ay[8] = {0.f, 0.f, 0.f, 0.f, 0.f, 0.f, 0.f, 0.f};
#pragma unroll 4
        for (int d = 0; d < 256; d += 4) {
            const float2 e0 = *(const float2*)(E + (d + 0) * NUM_EMB + c0);
            const float2 e1 = *(const float2*)(E + (d + 1) * NUM_EMB + c0);
            const float2 e2 = *(const float2*)(E + (d + 2) * NUM_EMB + c0);
            const float2 e3 = *(const float2*)(E + (d + 3) * NUM_EMB + c0);
#pragma unroll
            for (int r = 0; r < 8; r++) {
                const float4 xv = *(const float4*)(&xs4[r][d]);
                ax[r] = fmaf(xv.x, e0.x, ax[r]); ay[r] = fmaf(xv.x, e0.y, ay[r]);
                ax[r] = fmaf(xv.y, e1.x, ax[r]); ay[r] = fmaf(xv.y, e1.y, ay[r]);
                ax[r] = fmaf(xv.z, e2.x, ax[r]); ay[r] = fmaf(xv.z, e2.y, ay[r]);
                ax[r] = fmaf(xv.w, e3.x, ax[r]); ay[r] = fmaf(xv.w, e3.y, ay[r]);
            }
        }
        const float2 ne = *(const float2*)(normE + c0);
#pragma unroll
        for (int r = 0; r < 8; r++) {
            if (r < nr) {
                const float f0 = (r2s[r] + ne.x) - 2.0f * ax[r];
                const float f1 = (r2s[r] + ne.y) - 2.0f * ay[r];
                u64 k0 = ((u64)sortable(f0) << 32) | (u32)c0;
                u64 k1 = ((u64)sortable(f1) << 32) | (u32)(c0 + 1);
                u64 km = umin64(k0, k1);
#pragma unroll
                for (int off = 32; off; off >>= 1) km = umin64(km, __shfl_xor(km, off, 64));
                if ((t & 63) == 0) wkey[r][t >> 6] = km;
            }
        }
        __syncthreads();
        if (t < 8 && t < nr) {
            u64 m = wkey[t][0];
#pragma unroll
            for (int w2 = 1; w2 < 8; w2++) m = umin64(m, wkey[t][w2]);
            const int row = (int)flaglist[b * 8 + t];
            idx_arr[row] = (u32)(m & 0xFFFFFFFFull);
            d_arr[row] = unsortable((u32)(m >> 32)) - r2s[t];   // exact dist - ||x||^2
        }
    }
}

// ---- out = gather(ET, idx); loss partial from nx2 + d_arr ----
__global__ __launch_bounds__(512) void vq_out(const float* __restrict__ ET,
                                              const u32* __restrict__ idx_arr,
                                              const float* __restrict__ nx2arr, const float* __restrict__ d_arr,
                                              float* __restrict__ out, float* __restrict__ partial) {
    const int t = threadIdx.x;
    const long long base = (long long)blockIdx.x * 4096;   // 16 rows * 256
    const int dcol = t & 255, half = t >> 8;
    if (t < 64) {
        float v = 0.f;
        if (t < 16) {
            const int row = blockIdx.x * 16 + t;
            v = nx2arr[row] + d_arr[row];
        }
#pragma unroll
        for (int off = 32; off; off >>= 1) v += __shfl_down(v, off, 64);
        if (t == 0) partial[blockIdx.x] = v;
    }
#pragma unroll
    for (int rr = 0; rr < 8; rr++) {
        const int r = half * 8 + rr;
        const int row = blockIdx.x * 16 + r;
        const u32 idx = idx_arr[row];
        out[base + r * EMB_DIM + dcol] = ET[(size_t)idx * EMB_DIM + dcol];
    }
}

// ---- finish: loss = m + 0.25*m ----
__global__ void vq_finish(const float* __restrict__ partial, float* __restrict__ loss_out) {
    __shared__ float red[256];
    const int t = threadIdx.x;
    float s = 0.f;
    for (int i = t; i < 2048; i += 256) s += partial[i];
    red[t] = s;
    __syncthreads();
    for (int k = 128; k > 0; k >>= 1) {
        if (t < k) red[t] += red[t + k];
        __syncthreads();
    }
    if (t == 0) {
        const float m = red[0] / 8388608.0f;
        loss_out[0] = fmaf(0.25f, m, m);
    }
}

extern "C" void kernel_launch(void* const* d_in, const int* in_sizes, int n_in,
                              void* d_out, int out_size, void* d_ws, size_t ws_size,
                              hipStream_t stream) {
    const float* X = (const float*)d_in[0];      // (32,32,32,256) fp32
    const float* E = (const float*)d_in[1];      // (256,1024) fp32
    float* out = (float*)d_out;

    // workspace layout (bytes) -- within proven extent
    char* ws = (char*)d_ws;
    float* ET       = (float*)(ws + 0);            // 1 MB
    float* normE    = (float*)(ws + 1048576);      // 4 KB
    float* partial  = (float*)(ws + 1052672);      // 8 KB
    char*  Es       = ws + 1060864;                // 512 KB (8 panels x 64KB)
    float* d_arr    = (float*)(ws + 3158016);      // 128 KB
    u32*   idx_arr  = (u32*)(ws + 3682304);        // 128 KB
    u32*   flaglist = (u32*)(ws + 3813376);        // 128 KB
    u32*   cnt      = (u32*)(ws + 3944448);        // 4 B
    float* mxparts  = (float*)(ws + 3944452);      // 16 B
    float* nx2arr   = (float*)(ws + 3944960);      // 128 KB (ends 4,076,032)

    // d_out scratch: Xs [0,16MB); xl2/xh2 [16MB,16.25MB); gkey 2MB + gm2 1MB above.
    // All dead before vq_out overwrites d_out.
    char*  Xs      = (char*)d_out;
    float* xl2arr  = (float*)((char*)d_out + 16777216);
    float* xh2arr  = (float*)((char*)d_out + 16777216 + 131072);
    u64*   gkey    = (u64*)((char*)d_out + 17039360);
    float* gm2     = (float*)((char*)d_out + 17039360 + 2097152);

    vq_prep<<<338, 512, 0, stream>>>(X, E, ET, normE, Es, Xs, xl2arr, xh2arr, nx2arr,
                                     mxparts, cnt);
    vq_gemm<<<1024, 512, 65536, stream>>>(Xs, Es, normE, gkey, gm2);
    vq_combine<<<64, 512, 0, stream>>>(gkey, gm2, xl2arr, xh2arr, mxparts,
                                       idx_arr, d_arr, flaglist, cnt);
    vq_recheck<<<1024, 512, 0, stream>>>(X, E, normE, flaglist, cnt, idx_arr, d_arr);
    vq_out<<<2048, 512, 0, stream>>>(ET, idx_arr, nx2arr, d_arr, out, partial);
    vq_finish<<<1, 256, 0, stream>>>(partial, out + (out_size - 1));
}